// Round 17
// baseline (184.782 us; speedup 1.0000x reference)
//
#include <hip/hip_runtime.h>

typedef __attribute__((ext_vector_type(4))) float f32x4;
typedef __attribute__((ext_vector_type(4))) int   i32x4;
typedef __attribute__((ext_vector_type(2))) unsigned int u32x2;

#define NBLK 1024
#define NTHR 256    // 4 waves; 64 KB LDS -> 2 blocks/CU
#define NT   32     // 16-row tiles: 1024 * 32 * 16 = 524288 rows
#define DOUT 128

__device__ __forceinline__ unsigned short bf_rne(float x) {
  unsigned u = __builtin_bit_cast(unsigned, x);
  return (unsigned short)((u + 0x7FFFu + ((u >> 16) & 1u)) >> 16);
}
// preamble-only: fp32 -> bf16 hi (truncate) + bf16 lo (RNE of residual)
__device__ __forceinline__ void split2(float x, short& hi, short& lo) {
  unsigned u = __builtin_bit_cast(unsigned, x);
  float hf = __builtin_bit_cast(float, u & 0xFFFF0000u);
  hi = (short)(unsigned short)(u >> 16);
  lo = (short)bf_rne(x - hf);
}
__device__ __forceinline__ float fbits(unsigned u) { return __builtin_bit_cast(float, u); }
// packed f32->bf16 RNE x2 (no builtin on gfx950 — T12 recipe)
__device__ __forceinline__ unsigned cvtpk(float a, float b) {
  unsigned r;
  asm("v_cvt_pk_bf16_f32 %0, %1, %2" : "=v"(r) : "v"(a), "v"(b));
  return r;
}
// async global->LDS, 16B/lane, per-lane global src + wave-uniform LDS base
__device__ __forceinline__ void gll16(const float* g, char* l) {
  __builtin_amdgcn_global_load_lds(
      (const __attribute__((address_space(1))) unsigned int*)g,
      (__attribute__((address_space(3))) unsigned int*)l, 16, 0, 0);
}
// MFMA: A (W) from AGPR, B (x) from VGPR, acc VGPR. s_nop guards the
// VALU->MFMA hazard across the asm boundary (R16-proven).
#define MFMA_AW(ACC, W, X)                                                   \
  asm("s_nop 1\n\tv_mfma_f32_16x16x32_bf16 %0, %1, %2, %0"                   \
      : "+v"(ACC) : "a"(W), "v"(X))

// R17: attack the measured bottleneck — LDS frag-read amplification.
// R13/R16 accounting: iter 8060 cyc/CU, LDS ~4600, of which 3072 = frag
// reads (8 waves re-reading the same 16KB tile; 2 ds_read_b128 per 3 MFMA).
// Fix: wave owns 32 cols -> W = 128 AGPRs ("a"-pinned; mirror half has the
// room, R16 law: total file = 512/(waves/EU)), 6 MFMA per read-pair, and only
// 4 waves cover 128 cols -> frag-read instrs per row halved. 256-thr blocks,
// 64 KB LDS, 2 blocks/CU. Occupancy stays ~25% BY DESIGN (R16 falsified the
// occupancy lever; BW comes from continuous DMA issue + counted vmcnt).
// LDS banking derived: F-read granules v+16q (uniform 8 words/bank, 0 conf);
// B frag layout l^ks (read = lane permutation, 0 conf); B-writes ~2-way.
__global__ __launch_bounds__(NTHR, 2)
void dagmm(const float* __restrict__ x0, const float* __restrict__ x1,
           const float* __restrict__ w0, const float* __restrict__ w1,
           const float* __restrict__ m0, const float* __restrict__ m1,
           float* __restrict__ out)
{
  __shared__ __align__(16) char L[65536];
  // F[r] = r*16384           : fp32 tile [16 rows][1024 B] (DMA dst, linear)
  // B[r] = 32768 + r*16384   : bf16 hi 8 KB (frag-major ks*1024), lo +8192

  const int t   = threadIdx.x;
  const int l   = t & 63;
  const int w   = t >> 6;       // wave 0..3 -> owns output cols [w*32, w*32+32)
  const int l16 = l & 15;
  const int lq  = l >> 4;

  // ---------- W preamble: masked + hi/lo-split, 2 col-tiles -> 128 AGPRs ----
  i32x4 WH[2][8], WL[2][8];
#pragma unroll
  for (int c = 0; c < 2; ++c) {
    const int col = w * 32 + c * 16 + l16;
#pragma unroll
    for (int ks = 0; ks < 8; ++ks) {
      const int k0 = ks * 32 + lq * 8;            // never straddles 128
      const float* wp = (k0 < 128) ? (w0 + col * 128 + k0) : (w1 + col * 128 + (k0 - 128));
      const float* mp = (k0 < 128) ? (m0 + col * 128 + k0) : (m1 + col * 128 + (k0 - 128));
      float4 wa = *(const float4*)wp, wb = *(const float4*)(wp + 4);
      float4 ma = *(const float4*)mp, mb = *(const float4*)(mp + 4);
      float v[8] = {wa.x*ma.x, wa.y*ma.y, wa.z*ma.z, wa.w*ma.w,
                    wb.x*mb.x, wb.y*mb.y, wb.z*mb.z, wb.w*mb.w};
      short hv[8], lv[8];
#pragma unroll
      for (int j = 0; j < 8; ++j) split2(v[j], hv[j], lv[j]);
      WH[c][ks] = __builtin_bit_cast(i32x4, *(f32x4*)0 == *(f32x4*)0 ? *(i32x4*)hv : *(i32x4*)hv);
      WH[c][ks] = *(const i32x4*)hv;
      WL[c][ks] = *(const i32x4*)lv;
      asm volatile("" : "+a"(WH[c][ks]));   // pin in AGPRs
      asm volatile("" : "+a"(WL[c][ks]));
    }
  }

  const size_t Tbase = (size_t)blockIdx.x * (NT * 16);
  // per-lane DMA source: lane covers floats [l*4, l*4+4) of a row's K=256
  const float* xsrc = (l < 32) ? (x0 + l * 4) : (x1 + (l - 32) * 4);

  // wave w DMAs rows w*4..w*4+3 (1 gll16 each, lane x 16B linear)
#define ISSUE(ts, fb)                                                        \
  {                                                                          \
    _Pragma("unroll")                                                        \
    for (int i = 0; i < 4; ++i) {                                            \
      const int row = w * 4 + i;                                             \
      const size_t grow = Tbase + (size_t)(ts) * 16 + row;                   \
      gll16(xsrc + grow * 128, L + (fb) + row * 1024);                       \
    }                                                                        \
  }

  // SPLIT: thread t handles row rS = t>>4 (its own wave's DMA rows),
  // granules vS+16q (stride-256B: uniform banks). cvt_pk RNE hi + residual lo.
  const int rS    = t >> 4;
  const int vS    = t & 15;
  const int lamS  = rS | (((vS >> 1) & 3) << 4);
  const int halfS = (vS & 1) * 8;

#define SPLIT(fb, bb)                                                        \
  {                                                                          \
    const char* Fb = L + (fb) + rS * 1024 + vS * 16;                         \
    f32x4 f0 = *(const f32x4*)(Fb);                                          \
    f32x4 f1 = *(const f32x4*)(Fb + 256);                                    \
    f32x4 f2 = *(const f32x4*)(Fb + 512);                                    \
    f32x4 f3 = *(const f32x4*)(Fb + 768);                                    \
    _Pragma("unroll")                                                        \
    for (int q = 0; q < 4; ++q) {                                            \
      f32x4 f = (q == 0) ? f0 : (q == 1) ? f1 : (q == 2) ? f2 : f3;          \
      unsigned h01 = cvtpk(f[0], f[1]);                                      \
      unsigned h23 = cvtpk(f[2], f[3]);                                      \
      float e0 = f[0] - fbits(h01 << 16);                                    \
      float e1 = f[1] - fbits(h01 & 0xffff0000u);                            \
      float e2 = f[2] - fbits(h23 << 16);                                    \
      float e3 = f[3] - fbits(h23 & 0xffff0000u);                            \
      u32x2 hv, lv;                                                          \
      hv[0] = h01; hv[1] = h23;                                              \
      lv[0] = cvtpk(e0, e1); lv[1] = cvtpk(e2, e3);                          \
      const int ksq = (vS >> 3) + 2 * q;                                     \
      char* p = L + (bb) + ksq * 1024 + ((lamS ^ ksq) << 4) + halfS;         \
      *(u32x2*)p          = hv;                                              \
      *(u32x2*)(p + 8192) = lv;                                              \
    }                                                                        \
  }

  // ---------- prologue: tiles 0,1 in flight; tile0 split -> B[0] ----------
  ISSUE(0, 0);
  ISSUE(1, 16384);
  asm volatile("s_waitcnt vmcnt(4)" ::: "memory");   // tile0's 4 rows landed
  SPLIT(0, 32768);
  asm volatile("s_waitcnt lgkmcnt(0)" ::: "memory");

  for (int tt = 0; tt < NT; ++tt) {
    const int r = tt & 1;

    // barrier: B[r] (tile tt) complete block-wide; F[r] fp32 fully consumed
    asm volatile("" ::: "memory");
    __builtin_amdgcn_s_barrier();
    asm volatile("" ::: "memory");

    // 1) DMA tile tt+2 into F[r] (clamped tail keeps vmcnt count uniform)
    { const int ts = (tt + 2 < NT) ? (tt + 2) : (NT - 1); ISSUE(ts, r * 16384); }

    // 2) own rows of tile tt+1 landed; tt+2's 4 loads stay in flight (never 0)
    asm volatile("s_waitcnt vmcnt(4)" ::: "memory");

    // 3) SPLIT(tt+1) -> B[r^1]   ||   MFMA(tt) from B[r]
    if (tt + 1 < NT) SPLIT((r ^ 1) * 16384, 32768 + (r ^ 1) * 16384);

    f32x4 acc0 = (f32x4){0.f, 0.f, 0.f, 0.f};
    f32x4 acc1 = (f32x4){0.f, 0.f, 0.f, 0.f};
    {
      const char* Bb = L + 32768 + r * 16384;
#pragma unroll
      for (int ks = 0; ks < 8; ++ks) {
        const char* bp = Bb + ks * 1024 + ((l ^ ks) << 4);
        i32x4 xh = *(const i32x4*)bp;
        i32x4 xl = *(const i32x4*)(bp + 8192);
        // W ~ WH+WL, X ~ xh+xl: 3 terms (drop WL*xl ~2^-30); acc0/acc1
        // interleaved to break the dependent MFMA chain
        MFMA_AW(acc0, WH[0][ks], xh);
        MFMA_AW(acc1, WH[1][ks], xh);
        MFMA_AW(acc0, WH[0][ks], xl);
        MFMA_AW(acc1, WH[1][ks], xl);
        MFMA_AW(acc0, WL[0][ks], xh);
        MFMA_AW(acc1, WL[1][ks], xh);
      }
    }
    asm volatile("s_nop 7\n\ts_nop 7" :::);   // MFMA-write -> store hazard

    // D (R13-verified): col(l16) = batch row, lq*4+reg = out col
    {
      const size_t row = Tbase + (size_t)tt * 16 + l16;
      *(f32x4*)&out[row * DOUT + w * 32 + lq * 4]      = acc0;
      *(f32x4*)&out[row * DOUT + w * 32 + 16 + lq * 4] = acc1;
    }

    // 4) drain ds ops only; global loads (tt+2) stay in flight
    asm volatile("s_waitcnt lgkmcnt(0)" ::: "memory");
  }
#undef ISSUE
#undef SPLIT
}

extern "C" void kernel_launch(void* const* d_in, const int* in_sizes, int n_in,
                              void* d_out, int out_size, void* d_ws, size_t ws_size,
                              hipStream_t stream) {
  const float* x0 = (const float*)d_in[0];
  const float* x1 = (const float*)d_in[1];
  const float* w0 = (const float*)d_in[2];
  const float* w1 = (const float*)d_in[3];
  const float* m0 = (const float*)d_in[4];
  const float* m1 = (const float*)d_in[5];
  dagmm<<<NBLK, NTHR, 0, stream>>>(x0, x1, w0, w1, m0, m1, (float*)d_out);
}

// Round 18
// 173.895 us; speedup vs baseline: 1.0626x; 1.0626x over previous
//
#include <hip/hip_runtime.h>

typedef __attribute__((ext_vector_type(4))) float f32x4;
typedef __attribute__((ext_vector_type(4))) int   i32x4;
typedef __attribute__((ext_vector_type(2))) unsigned int u32x2;

#define NBLK 512
#define NTHR 512    // 8 waves; 96 KB LDS -> 1 block/CU (R13 residency)
#define NT   32     // 32-row tiles: 512 * 32 * 32 = 524288 rows
#define DOUT 128

__device__ __forceinline__ unsigned short bf_rne(float x) {
  unsigned u = __builtin_bit_cast(unsigned, x);
  return (unsigned short)((u + 0x7FFFu + ((u >> 16) & 1u)) >> 16);
}
// W preamble: fp32 -> bf16 hi (truncate) + bf16 lo (RNE of residual)
__device__ __forceinline__ void split2(float x, short& hi, short& lo) {
  unsigned u = __builtin_bit_cast(unsigned, x);
  float hf = __builtin_bit_cast(float, u & 0xFFFF0000u);
  hi = (short)(unsigned short)(u >> 16);
  lo = (short)bf_rne(x - hf);
}
// packed f32->bf16 RNE x2 (no builtin on gfx950)
__device__ __forceinline__ unsigned cvtpk(float a, float b) {
  unsigned r;
  asm("v_cvt_pk_bf16_f32 %0, %1, %2" : "=v"(r) : "v"(a), "v"(b));
  return r;
}
// async global->LDS, 16B/lane, per-lane global src + wave-uniform LDS base
__device__ __forceinline__ void gll16(const float* g, char* l) {
  __builtin_amdgcn_global_load_lds(
      (const __attribute__((address_space(1))) unsigned int*)g,
      (__attribute__((address_space(3))) unsigned int*)l, 16, 0, 0);
}
// MFMA: A (W) from AGPR, B (x) from VGPR, acc VGPR. s_nop guards the
// VALU->MFMA hazard across the asm boundary (R16/R17-proven).
#define MFMA_AW(ACC, W, X)                                                   \
  asm("s_nop 1\n\tv_mfma_f32_16x16x32_bf16 %0, %1, %2, %0"                   \
      : "+v"(ACC) : "a"(W), "v"(X))

// R18: shorten the per-iteration serial chain (R13-R17 all pinned at
// ~6580 cyc/block-iter regardless of occupancy/layout — chain-bound).
// Numerics: x single RNE-bf16 plane, W hi/lo 2-term (x16*(wh+wl)).
//   err: dx<=2^-9|x| vs w(rms .1, ~64 active) -> +~5e-3 max; R16 passed
//   at absmax 0.03125, predicted here ~0.02.
// Cuts per tile: MFMA 3->2, frag-reads halved (1 b128 per 2 MFMA), SPLIT
// halved (cvt_pk, one plane), B 32->16 KB.
// Base = R13 cadence (best bench 175.5) with 2 fixes:
//   vmcnt(4) (R13's vmcnt(6) was a benign-by-timing race: tile t+1 needs
//   all 4 own-wave loads), and granule-interleaved F-read (stride-256B,
//   uniform 8 words/bank = inherent; R13's consecutive-64B was 8-way).
// F is PER-WAVE private (DMA + SPLIT touch only own rows) -> barriers only
// protect B. W in AGPRs ("a"-pinned, R16: VGPR=64).
__global__ __launch_bounds__(NTHR, 2)
void dagmm(const float* __restrict__ x0, const float* __restrict__ x1,
           const float* __restrict__ w0, const float* __restrict__ w1,
           const float* __restrict__ m0, const float* __restrict__ m1,
           float* __restrict__ out)
{
  __shared__ __align__(16) char L[98304];
  // F[r] = r*32768         : fp32 tile [32 rows][1024 B] (DMA dst, linear)
  // B[r] = 65536 + r*16384 : bf16 x-frags, 16 frags x 1 KB
  const int t   = threadIdx.x;
  const int l   = t & 63;
  const int w   = t >> 6;       // wave 0..7 -> owns output cols [w*16, w*16+16)
  const int l16 = l & 15;
  const int lq  = l >> 4;

  // ---------- W preamble: masked, hi/lo-split A-frags -> AGPRs ----------
  // lane: A-row(=out col) = w*16+l16, k = ks*32 + lq*8 + j
  i32x4 WH[8], WL[8];
  {
    const int col = w * 16 + l16;
#pragma unroll
    for (int ks = 0; ks < 8; ++ks) {
      const int k0 = ks * 32 + lq * 8;            // never straddles 128
      const float* wp = (k0 < 128) ? (w0 + col * 128 + k0) : (w1 + col * 128 + (k0 - 128));
      const float* mp = (k0 < 128) ? (m0 + col * 128 + k0) : (m1 + col * 128 + (k0 - 128));
      float4 wa = *(const float4*)wp, wb = *(const float4*)(wp + 4);
      float4 ma = *(const float4*)mp, mb = *(const float4*)(mp + 4);
      float v[8] = {wa.x*ma.x, wa.y*ma.y, wa.z*ma.z, wa.w*ma.w,
                    wb.x*mb.x, wb.y*mb.y, wb.z*mb.z, wb.w*mb.w};
      short hv[8], lv[8];
#pragma unroll
      for (int j = 0; j < 8; ++j) split2(v[j], hv[j], lv[j]);
      WH[ks] = *(const i32x4*)hv;
      WL[ks] = *(const i32x4*)lv;
      asm volatile("" : "+a"(WH[ks]));   // pin in AGPRs (mirror half)
      asm volatile("" : "+a"(WL[ks]));
    }
  }

  const size_t Tbase = (size_t)blockIdx.x * (NT * 32);
  // per-lane DMA source: lane covers floats [l*4, l*4+4) of a row's K=256
  const float* xsrc = (l < 32) ? (x0 + l * 4) : (x1 + (l - 32) * 4);

  // wave w DMAs its own rows w*4..w*4+3 (1 KB each, lane x 16B linear)
#define ISSUE(ts, r)                                                         \
  {                                                                          \
    _Pragma("unroll")                                                        \
    for (int i = 0; i < 4; ++i) {                                            \
      const int row = w * 4 + i;                                             \
      const size_t grow = Tbase + (size_t)(ts) * 32 + row;                   \
      gll16(xsrc + grow * 128, L + (r) * 32768 + row * 1024);                \
    }                                                                        \
  }

  // SPLIT: own-wave rows, granule-interleaved F-read (g = v + 16q), RNE
  // convert, write 8B halves into frag layout (slot = lam^ks, XOR involution)
  const int rowS = w * 4 + (l >> 4);    // own wave's row
  const int vS   = l & 15;
#define SPLIT(r)                                                             \
  {                                                                          \
    const char* Fb = L + (r) * 32768 + rowS * 1024;                          \
    char*       Bb = L + 65536 + (r) * 16384 + (rowS >> 4) * 8192;           \
    _Pragma("unroll")                                                        \
    for (int q = 0; q < 4; ++q) {                                            \
      const int g = vS + 16 * q;              /* granule: floats 4g..4g+3 */ \
      f32x4 f = *(const f32x4*)(Fb + g * 16);                                \
      u32x2 hv;                                                              \
      hv[0] = cvtpk(f[0], f[1]);                                             \
      hv[1] = cvtpk(f[2], f[3]);                                             \
      const int ks   = g >> 3;                                               \
      const int lam  = (rowS & 15) | (((g >> 1) & 3) << 4);                  \
      char* p = Bb + ks * 1024 + ((lam ^ ks) << 4) + (g & 1) * 8;            \
      *(u32x2*)p = hv;                                                       \
    }                                                                        \
  }

  // ---------- prologue: tiles 0,1 in flight ----------
  ISSUE(0, 0);
  ISSUE(1, 1);

  for (int tt = 0; tt < NT; ++tt) {
    const int r = tt & 1;

    // 1) own rows of tile tt landed; tile tt+1's 4 stay in flight (never 0)
    asm volatile("s_waitcnt vmcnt(4)" ::: "memory");

    // 2) SPLIT tile tt: F[r] -> B[r] (own rows; F is per-wave private)
    SPLIT(r);
    asm volatile("s_waitcnt lgkmcnt(0)" ::: "memory");
    __builtin_amdgcn_s_barrier();          // B[r] complete block-wide

    // 3) DMA tile tt+2 into F[r] (own rows just consumed by SPLIT above)
    { const int ts = (tt + 2 < NT) ? (tt + 2) : (NT - 1); ISSUE(ts, r); }

    // 4) MFMA(tt): 8 ks x 2 rt x {1 frag read + 2 MFMA}
    f32x4 acc0 = (f32x4){0.f, 0.f, 0.f, 0.f};
    f32x4 acc1 = (f32x4){0.f, 0.f, 0.f, 0.f};
    {
      const char* Bb = L + 65536 + r * 16384;
#pragma unroll
      for (int ks = 0; ks < 8; ++ks) {
        const char* p0 = Bb + ks * 1024 + ((l ^ ks) << 4);
        i32x4 xa = *(const i32x4*)p0;
        i32x4 xb = *(const i32x4*)(p0 + 8192);
        MFMA_AW(acc0, WH[ks], xa);
        MFMA_AW(acc1, WH[ks], xb);
        MFMA_AW(acc0, WL[ks], xa);
        MFMA_AW(acc1, WL[ks], xb);
      }
    }
    asm volatile("s_nop 7\n\ts_nop 7" :::);   // MFMA-write -> store hazard

    // D (R13-verified): col(l16) = batch row, lq*4+reg = out col -> f32x4
    {
      const size_t row0 = Tbase + (size_t)tt * 32 + l16;
      *(f32x4*)&out[(row0     ) * DOUT + w * 16 + lq * 4] = acc0;
      *(f32x4*)&out[(row0 + 16) * DOUT + w * 16 + lq * 4] = acc1;
    }

    // 5) all frag reads of B[r] retired block-wide before its next overwrite
    asm volatile("s_waitcnt lgkmcnt(0)" ::: "memory");
    __builtin_amdgcn_s_barrier();
  }
#undef ISSUE
#undef SPLIT
}

extern "C" void kernel_launch(void* const* d_in, const int* in_sizes, int n_in,
                              void* d_out, int out_size, void* d_ws, size_t ws_size,
                              hipStream_t stream) {
  const float* x0 = (const float*)d_in[0];
  const float* x1 = (const float*)d_in[1];
  const float* w0 = (const float*)d_in[2];
  const float* w1 = (const float*)d_in[3];
  const float* m0 = (const float*)d_in[4];
  const float* m1 = (const float*)d_in[5];
  dagmm<<<NBLK, NTHR, 0, stream>>>(x0, x1, w0, w1, m0, m1, (float*)d_out);
}

// Round 19
// 172.545 us; speedup vs baseline: 1.0709x; 1.0078x over previous
//
#include <hip/hip_runtime.h>

typedef __attribute__((ext_vector_type(4))) float f32x4;
typedef __attribute__((ext_vector_type(4))) int   i32x4;
typedef __attribute__((ext_vector_type(2))) unsigned int u32x2;

#define NBLK 512
#define NTHR 512    // 8 waves; 64 KB LDS; VGPR -> 8 waves/CU (1 block resident)
#define NT   16     // 64-row tiles: 512 * 16 * 64 = 524288 rows
#define DOUT 128

// W preamble: fp32 -> bf16 hi (truncate) + bf16 lo (RNE of residual)
__device__ __forceinline__ void split2(float x, short& hi, short& lo) {
  unsigned u = __builtin_bit_cast(unsigned, x);
  float hf = __builtin_bit_cast(float, u & 0xFFFF0000u);
  hi = (short)(unsigned short)(u >> 16);
  unsigned v = __builtin_bit_cast(unsigned, x - hf);
  lo = (short)(unsigned short)((v + 0x7FFFu + ((v >> 16) & 1u)) >> 16);
}
// packed f32->bf16 RNE x2 (no builtin on gfx950)
__device__ __forceinline__ unsigned cvtpk(float a, float b) {
  unsigned r;
  asm("v_cvt_pk_bf16_f32 %0, %1, %2" : "=v"(r) : "v"(a), "v"(b));
  return r;
}
// MFMA: A (W) from AGPR, B (x) from VGPR, acc VGPR. s_nop guards the
// VALU->MFMA hazard across the asm boundary (R16-R18 proven).
#define MFMA_AW(ACC, W, X)                                                   \
  asm("s_nop 1\n\tv_mfma_f32_16x16x32_bf16 %0, %1, %2, %0"                   \
      : "+v"(ACC) : "a"(W), "v"(X))

// R19: halve the iteration count (exposure model from R10/R18 cross-fit:
// dur = N_iter x ~2500cyc stall + work; R18 paid 64 exposures = ~67us).
//  - 64-row tiles, reg-staged (R10 skeleton: 8 coalesced float4/thread,
//    proven 104 VGPR no-spill), NT=16 -> 32 exposures total (2 block rounds).
//  - x single RNE-bf16 plane + W hi/lo in AGPRs (R18 numerics, absmax .031).
//  - ONE barrier/iter: B double-buffered; reads of B[r] at iter t precede
//    barrier(t+1) (program order), overwrites at t+2 follow it. Barrier #2
//    (R18) was redundant.
//  - B frag layout: f = rt*8+ks (32 frags x 1KB), slot XOR f&31; read is a
//    lane permutation (0-conflict); write == R18's proven path per-frag.
__global__ __launch_bounds__(NTHR, 2)
void dagmm(const float* __restrict__ x0, const float* __restrict__ x1,
           const float* __restrict__ w0, const float* __restrict__ w1,
           const float* __restrict__ m0, const float* __restrict__ m1,
           float* __restrict__ out)
{
  __shared__ __align__(16) char L[65536];   // B[2] x 32 KB bf16 x-frags

  const int t   = threadIdx.x;
  const int l   = t & 63;
  const int w   = t >> 6;       // wave 0..7 -> owns output cols [w*16, w*16+16)
  const int l16 = l & 15;
  const int lq  = l >> 4;

  // ---------- W preamble: masked, hi/lo-split A-frags -> AGPRs ----------
  // lane: A-row(=out col) = w*16+l16, k = ks*32 + lq*8 + j
  i32x4 WH[8], WL[8];
  {
    const int col = w * 16 + l16;
#pragma unroll
    for (int ks = 0; ks < 8; ++ks) {
      const int k0 = ks * 32 + lq * 8;            // never straddles 128
      const float* wp = (k0 < 128) ? (w0 + col * 128 + k0) : (w1 + col * 128 + (k0 - 128));
      const float* mp = (k0 < 128) ? (m0 + col * 128 + k0) : (m1 + col * 128 + (k0 - 128));
      float4 wa = *(const float4*)wp, wb = *(const float4*)(wp + 4);
      float4 ma = *(const float4*)mp, mb = *(const float4*)(mp + 4);
      float v[8] = {wa.x*ma.x, wa.y*ma.y, wa.z*ma.z, wa.w*ma.w,
                    wb.x*mb.x, wb.y*mb.y, wb.z*mb.z, wb.w*mb.w};
      short hv[8], lv[8];
#pragma unroll
      for (int j = 0; j < 8; ++j) split2(v[j], hv[j], lv[j]);
      WH[ks] = *(const i32x4*)hv;
      WL[ks] = *(const i32x4*)lv;
      asm volatile("" : "+a"(WH[ks]));   // pin in AGPRs (mirror half)
      asm volatile("" : "+a"(WL[ks]));
    }
  }

  const size_t Tbase = (size_t)blockIdx.x * (NT * 64);
  // per-lane source: lane covers floats [l*4, l*4+4) of a row's K=256
  const float* xb = (l < 32) ? (x0 + l * 4) : (x1 + (l - 32) * 4);

  // stage: wave w holds rows w*8..w*8+7, 16B/lane each (coalesced 1KB/instr)
  float4 pf[8];
#define LOADSTAGE(ts)                                                        \
  {                                                                          \
    _Pragma("unroll")                                                        \
    for (int s = 0; s < 8; ++s)                                              \
      pf[s] = *(const float4*)(xb + (Tbase + (size_t)(ts) * 64 + w * 8 + s) * 128); \
  }

  // CVT+WRITE: row = w*8+s, 4 floats at k0 = l*4 -> u32x2 (8B) into frag
  // f = (row>>4)*8 + (l>>3); lam = (row&15) | (((l>>1)&3)<<4); half = (l&1)*8
#define CVTWRITE(bb)                                                         \
  {                                                                          \
    _Pragma("unroll")                                                        \
    for (int s = 0; s < 8; ++s) {                                            \
      const int row = w * 8 + s;                                             \
      u32x2 hv;                                                              \
      hv[0] = cvtpk(pf[s].x, pf[s].y);                                       \
      hv[1] = cvtpk(pf[s].z, pf[s].w);                                       \
      const int f   = (row >> 4) * 8 + (l >> 3);                             \
      const int lam = (row & 15) | (((l >> 1) & 3) << 4);                    \
      char* p = L + (bb) + f * 1024 + ((lam ^ (f & 31)) << 4) + (l & 1) * 8; \
      *(u32x2*)p = hv;                                                       \
    }                                                                        \
  }

  // ---------- prologue ----------
  LOADSTAGE(0);

  for (int tt = 0; tt < NT; ++tt) {
    const int bb = (tt & 1) * 32768;

    // 1) convert staged tile tt -> B[r] (frees pf), then refill pf (tile tt+1)
    CVTWRITE(bb);
    if (tt + 1 < NT) LOADSTAGE(tt + 1);   // in flight across barrier + MFMA

    // 2) the ONLY barrier: B[r] visible block-wide (ds writes drained)
    asm volatile("s_waitcnt lgkmcnt(0)" ::: "memory");
    __builtin_amdgcn_s_barrier();
    asm volatile("" ::: "memory");

    // 3) MFMA(tt): 4 rt x 8 ks x {1 b128 read + 2 MFMA (hi,lo)}
    f32x4 acc[4];
#pragma unroll
    for (int rt = 0; rt < 4; ++rt) acc[rt] = (f32x4){0.f, 0.f, 0.f, 0.f};
#pragma unroll
    for (int ks = 0; ks < 8; ++ks) {
#pragma unroll
      for (int rt = 0; rt < 4; ++rt) {
        const int f = rt * 8 + ks;
        const char* p = L + bb + f * 1024 + ((l ^ (f & 31)) << 4);
        i32x4 xh = *(const i32x4*)p;
        MFMA_AW(acc[rt], WH[ks], xh);
        MFMA_AW(acc[rt], WL[ks], xh);
      }
    }
    asm volatile("s_nop 7\n\ts_nop 7" :::);   // MFMA-write -> store hazard

    // 4) D (R13-verified): col(l16) = batch row, lq*4+reg = out col
#pragma unroll
    for (int rt = 0; rt < 4; ++rt) {
      const size_t row = Tbase + (size_t)tt * 64 + rt * 16 + l16;
      *(f32x4*)&out[row * DOUT + w * 16 + lq * 4] = acc[rt];
    }
    // no second barrier: next overwrite of B[r] is at iter tt+2, ordered by
    // barrier(tt+1); this wave's B[r] reads retired before it issues that.
  }
#undef LOADSTAGE
#undef CVTWRITE
}

extern "C" void kernel_launch(void* const* d_in, const int* in_sizes, int n_in,
                              void* d_out, int out_size, void* d_ws, size_t ws_size,
                              hipStream_t stream) {
  const float* x0 = (const float*)d_in[0];
  const float* x1 = (const float*)d_in[1];
  const float* w0 = (const float*)d_in[2];
  const float* w1 = (const float*)d_in[3];
  const float* m0 = (const float*)d_in[4];
  const float* m1 = (const float*)d_in[5];
  dagmm<<<NBLK, NTHR, 0, stream>>>(x0, x1, w0, w1, m0, m1, (float*)d_out);
}